// Round 16
// baseline (196.598 us; speedup 1.0000x reference)
//
#include <hip/hip_runtime.h>

#define N_TRAIN 100000
#define N_DIM   256
#define BATCH   16384
#define QUARTER 25000

// out[i,j] = order[ clip(floor(Phi(noise[i,j]) * N_TRAIN), 0, N_TRAIN-1), j ]
//
// Round-15: ONE stripe per XCD at a time.
// 512 blocks = 2 WG/CU, exactly co-resident. Block bid handles row-chunk
// (bid>>3)*256..+255 for stripe (bid&7), THEN stripe (bid&7)+8. With the
// bid%8 -> XCD round-robin, XCD x's 64 resident blocks all process stripe x
// together (then x+8), so the per-XCD L2 working set is one stripe-quarter
// (~1.6 MB, +drift ~3.2 MB) < 4 MB -> near-full line retention. Each 64B
// line of `order` serves all 16 columns' gathers of the stripe from L2.
//
// Index-range quartering (idx/25000, 4 predicated passes) keeps the active
// quantile-row range small; __syncthreads between passes bounds intra-block
// drift. Results buffered in registers (fully unrolled, static indexing),
// one float4 NT store per row-step. noise/out NT so streams don't evict
// the stripe from L2.

typedef float vfloat4 __attribute__((ext_vector_type(4)));

__global__ __launch_bounds__(256) void icdf_stripe_q2_kernel(
    const float* __restrict__ noise,
    const float* __restrict__ order,
    float* __restrict__ out)
{
    const int bid  = blockIdx.x;
    const int sgrp = bid & 7;          // XCD-affine stripe group
    const int i0   = (bid >> 3) * 256; // row chunk (64 chunks of 256 rows)

    const int lane_col = (threadIdx.x & 3) * 4;  // 0,4,8,12 within stripe
    const int row_off  = threadIdx.x >> 2;       // 0..63

    const float kInvSqrt2 = 0.70710678118654752440f;
    const float kN = (float)N_TRAIN;

    #pragma unroll
    for (int sp = 0; sp < 2; ++sp) {
        const int stripe = sgrp + (sp << 3);     // x then x+8
        const int jbase  = stripe * 16 + lane_col;

        int    idxs[4][4];
        float  res [4][4];
        size_t ebase[4];

        // ---- compute phase: 16 indices into registers ----
        #pragma unroll
        for (int p = 0; p < 4; ++p) {
            const int i = i0 + row_off + (p << 6);
            const size_t e = (size_t)i * N_DIM + jbase;
            ebase[p] = e;

            const vfloat4 nv = __builtin_nontemporal_load(
                reinterpret_cast<const vfloat4*>(noise + e));

            float u0 = 0.5f * erfcf(-nv.x * kInvSqrt2);
            float u1 = 0.5f * erfcf(-nv.y * kInvSqrt2);
            float u2 = 0.5f * erfcf(-nv.z * kInvSqrt2);
            float u3 = 0.5f * erfcf(-nv.w * kInvSqrt2);

            int a = (int)floorf(u0 * kN);
            int b = (int)floorf(u1 * kN);
            int c = (int)floorf(u2 * kN);
            int d = (int)floorf(u3 * kN);

            idxs[p][0] = min(max(a, 0), N_TRAIN - 1);
            idxs[p][1] = min(max(b, 0), N_TRAIN - 1);
            idxs[p][2] = min(max(c, 0), N_TRAIN - 1);
            idxs[p][3] = min(max(d, 0), N_TRAIN - 1);
        }

        // ---- gather passes: one quantile-row quarter at a time ----
        #pragma unroll
        for (int q = 0; q < 4; ++q) {
            const int lo = q * QUARTER;
            const int hi = lo + QUARTER;
            __syncthreads();           // bound intra-block pass drift
            #pragma unroll
            for (int p = 0; p < 4; ++p) {
                #pragma unroll
                for (int k = 0; k < 4; ++k) {
                    const int ix = idxs[p][k];
                    if (ix >= lo && ix < hi) {
                        res[p][k] = order[(size_t)ix * N_DIM + (jbase + k)];
                    }
                }
            }
        }

        // ---- store phase: full float4 NT stores ----
        #pragma unroll
        for (int p = 0; p < 4; ++p) {
            vfloat4 o;
            o.x = res[p][0];
            o.y = res[p][1];
            o.z = res[p][2];
            o.w = res[p][3];
            __builtin_nontemporal_store(o,
                reinterpret_cast<vfloat4*>(out + ebase[p]));
        }
    }
}

extern "C" void kernel_launch(void* const* d_in, const int* in_sizes, int n_in,
                              void* d_out, int out_size, void* d_ws, size_t ws_size,
                              hipStream_t stream)
{
    const float* noise = (const float*)d_in[0];
    const float* order = (const float*)d_in[1];
    float* out = (float*)d_out;

    // 512 blocks: 64 chunks x 8 stripe-groups; each block does 2 stripes.
    icdf_stripe_q2_kernel<<<512, 256, 0, stream>>>(noise, order, out);
}